// Round 6
// baseline (314.914 us; speedup 1.0000x reference)
//
#include <hip/hip_runtime.h>

#define T_DEPTH 200000
#define V_DIM   130
#define H_DIM   512

// d_out offsets (fp32 elements): ot, Val, stg, rt, h_new, c_new
#define OT_OFF   0
#define VAL_OFF  512
#define STG_OFF  26000642
#define RT_OFF   26200643
#define HN_OFF   26200773
#define CN_OFF   26201797

// ws offsets (floats) — all written before read, no memset needed
#define WS_H1    64
#define WS_C1    576
#define WS_H2    1088
#define WS_C2    1600

#define NV4 6500000   // T*V/4
#define NS2 100000    // T/2
#define CB  1024      // copy blocks: S = 262144 workers, ~25 units/thread, 8-deep batches

// ext-vector types (required by __builtin_nontemporal_*; HIP float4 is a struct)
typedef float f32x4 __attribute__((ext_vector_type(4)));
typedef float f32x2 __attribute__((ext_vector_type(2)));

static __device__ __forceinline__ float sigmoidf_(float x) {
  return 1.0f / (1.0f + expf(-x));
}

// ---- big copy, 8 loads in flight per thread. Cached loads (keep prev_Val L3
// hits, ~50% observed), nontemporal stores (Val body never re-read; don't
// evict prev_Val from L3 with the 102 MB write stream).
__global__ void k_bulk8(const f32x4* __restrict__ vin,
                        const f32x2* __restrict__ sin2,
                        float* __restrict__ out) {
  f32x4* __restrict__ vout = reinterpret_cast<f32x4*>(out + VAL_OFF);
  const int S = gridDim.x * blockDim.x;              // 262144
  const int w = blockIdx.x * blockDim.x + threadIdx.x;
  int u = w;
  for (; u + 7 * S < NV4; u += 8 * S) {
    f32x4 a0 = vin[u];
    f32x4 a1 = vin[u + S];
    f32x4 a2 = vin[u + 2 * S];
    f32x4 a3 = vin[u + 3 * S];
    f32x4 a4 = vin[u + 4 * S];
    f32x4 a5 = vin[u + 5 * S];
    f32x4 a6 = vin[u + 6 * S];
    f32x4 a7 = vin[u + 7 * S];
    __builtin_nontemporal_store(a0, vout + u);
    __builtin_nontemporal_store(a1, vout + u + S);
    __builtin_nontemporal_store(a2, vout + u + 2 * S);
    __builtin_nontemporal_store(a3, vout + u + 3 * S);
    __builtin_nontemporal_store(a4, vout + u + 4 * S);
    __builtin_nontemporal_store(a5, vout + u + 5 * S);
    __builtin_nontemporal_store(a6, vout + u + 6 * S);
    __builtin_nontemporal_store(a7, vout + u + 7 * S);
  }
  for (; u < NV4; u += S) {
    f32x4 a = vin[u];
    __builtin_nontemporal_store(a, vout + u);
  }
  // stg body copy (head rows fixed later by ktail, stream-ordered after us)
  f32x2* __restrict__ sout = reinterpret_cast<f32x2*>(out + STG_OFF);
  for (int v = w; v < NS2; v += S) sout[v] = sin2[v];
}

// one wave computes all 4 gate dots for unit j, then lane 0 applies the cell.
// (verified rounds 3-5) x = x_a (+ x_b if non-null)
static __device__ __forceinline__ void lstm_unit(
    const float* __restrict__ Wih, int in_dim,
    const float* __restrict__ x_a, const float* __restrict__ x_b,
    const float* __restrict__ Whh, const float* __restrict__ hprev,
    const float* __restrict__ bih, const float* __restrict__ bhh,
    const float* __restrict__ cprev, int j, int lane,
    float* __restrict__ h_ws, float* __restrict__ c_ws,
    float* __restrict__ h_out, float* __restrict__ c_out) {
  float pg[4];
#pragma unroll
  for (int q = 0; q < 4; ++q) {
    int row = q * H_DIM + j;
    const float* wr = Wih + row * in_dim;
    const float* wh = Whh + row * H_DIM;
    float acc = 0.f;
    if (x_b) {
      for (int c = lane; c < in_dim; c += 64) acc += wr[c] * (x_a[c] + x_b[c]);
    } else {
      for (int c = lane; c < in_dim; c += 64) acc += wr[c] * x_a[c];
    }
    for (int k = lane; k < H_DIM; k += 64) acc += wh[k] * hprev[k];
    for (int off = 32; off; off >>= 1) acc += __shfl_down(acc, off, 64);
    pg[q] = acc;  // total valid on lane 0
  }
  if (lane == 0) {
    float ig = sigmoidf_(pg[0] + bih[j] + bhh[j]);
    float fg = sigmoidf_(pg[1] + bih[H_DIM + j] + bhh[H_DIM + j]);
    float gg = tanhf(pg[2] + bih[2 * H_DIM + j] + bhh[2 * H_DIM + j]);
    float og = sigmoidf_(pg[3] + bih[3 * H_DIM + j] + bhh[3 * H_DIM + j]);
    float cn = fg * cprev[j] + ig * gg;
    float hn = og * tanhf(cn);
    h_ws[j] = hn; c_ws[j] = cn;
    h_out[j] = hn; c_out[j] = cn;
  }
}

// ---- fused layer-0 gates + cell: 128 blocks, wave per unit
__global__ void kL0(const float* __restrict__ Wih, const float* __restrict__ Whh,
                    const float* __restrict__ bih, const float* __restrict__ bhh,
                    const float* __restrict__ inp, const float* __restrict__ prd,
                    const float* __restrict__ hprev, const float* __restrict__ cprev,
                    float* __restrict__ ws, float* __restrict__ out) {
  int j = blockIdx.x * 4 + (threadIdx.x >> 6), lane = threadIdx.x & 63;
  lstm_unit(Wih, V_DIM, inp, prd, Whh, hprev, bih, bhh, cprev, j, lane,
            ws + WS_H1, ws + WS_C1, out + HN_OFF, out + CN_OFF);
}

// ---- fused layer-1 gates + cell
__global__ void kL1(const float* __restrict__ Wih, const float* __restrict__ Whh,
                    const float* __restrict__ bih, const float* __restrict__ bhh,
                    const float* __restrict__ hprev, const float* __restrict__ cprev,
                    float* __restrict__ ws, float* __restrict__ out) {
  int j = blockIdx.x * 4 + (threadIdx.x >> 6), lane = threadIdx.x & 63;
  lstm_unit(Wih, H_DIM, ws + WS_H1, nullptr, Whh, hprev, bih, bhh, cprev, j, lane,
            ws + WS_H2, ws + WS_C2, out + HN_OFF + H_DIM, out + CN_OFF + H_DIM);
}

// ---- fused tail: heads + finalize + top-of-stack walk, 4 independent blocks.
// Block 3 recomputes dt/ut/vt locally (~67K MACs) so it has no cross-block deps.
__global__ void ktail(const float* __restrict__ Wv, const float* __restrict__ Bv,
                      const float* __restrict__ Wo, const float* __restrict__ Bo,
                      const float* __restrict__ Wd, const float* __restrict__ Bd,
                      const float* __restrict__ Wu, const float* __restrict__ Bu,
                      const float* __restrict__ prev_stg, const float* __restrict__ prev_val,
                      const float* __restrict__ ws, float* __restrict__ out) {
  int bid = blockIdx.x, tid = threadIdx.x;
  const float* h2 = ws + WS_H2;
  if (bid < 2) {
    // ot columns
    int t = bid * 256 + tid;
    float a0 = 0.f, a1 = 0.f, a2 = 0.f, a3 = 0.f;
    for (int k = 0; k < H_DIM; k += 4) {
      a0 += h2[k]     * Wo[k * H_DIM + t];
      a1 += h2[k + 1] * Wo[(k + 1) * H_DIM + t];
      a2 += h2[k + 2] * Wo[(k + 2) * H_DIM + t];
      a3 += h2[k + 3] * Wo[(k + 3) * H_DIM + t];
    }
    out[OT_OFF + t] = tanhf(((a0 + a1) + (a2 + a3)) + Bo[t]);
  } else if (bid == 2) {
    // vt -> Val row T (output only; walk block computes its own copy)
    if (tid < V_DIM) {
      float a0 = 0.f, a1 = 0.f, a2 = 0.f, a3 = 0.f;
      for (int k = 0; k < H_DIM; k += 4) {
        a0 += h2[k]     * Wv[k * V_DIM + tid];
        a1 += h2[k + 1] * Wv[(k + 1) * V_DIM + tid];
        a2 += h2[k + 2] * Wv[(k + 2) * V_DIM + tid];
        a3 += h2[k + 3] * Wv[(k + 3) * V_DIM + tid];
      }
      out[VAL_OFF + T_DEPTH * V_DIM + tid] = tanhf(((a0 + a1) + (a2 + a3)) + Bv[tid]);
    }
  } else {
    // walk block: local dt/ut (block reduce), local vt, then exact pop+read walk
    __shared__ float red[256];
    __shared__ float s_dt, s_ut;
    float pd = h2[tid] * Wd[tid] + h2[tid + 256] * Wd[tid + 256];
    float pu = h2[tid] * Wu[tid] + h2[tid + 256] * Wu[tid + 256];
    red[tid] = pd;
    __syncthreads();
    for (int s = 128; s; s >>= 1) {
      if (tid < s) red[tid] += red[tid + s];
      __syncthreads();
    }
    if (tid == 0) s_dt = sigmoidf_(red[0] + Bd[0]);
    __syncthreads();
    red[tid] = pu;
    __syncthreads();
    for (int s = 128; s; s >>= 1) {
      if (tid < s) red[tid] += red[tid + s];
      __syncthreads();
    }
    if (tid == 0) s_ut = sigmoidf_(red[0] + Bu[0]);
    __syncthreads();
    float dt = s_dt;
    float u  = s_ut;    // pop carry (starts at ut)

    float vt_local = 0.f;
    if (tid < V_DIM) {
      float a0 = 0.f, a1 = 0.f, a2 = 0.f, a3 = 0.f;
      for (int k = 0; k < H_DIM; k += 4) {
        a0 += h2[k]     * Wv[k * V_DIM + tid];
        a1 += h2[k + 1] * Wv[(k + 1) * V_DIM + tid];
        a2 += h2[k + 2] * Wv[(k + 2) * V_DIM + tid];
        a3 += h2[k + 3] * Wv[(k + 3) * V_DIM + tid];
      }
      vt_local = tanhf(((a0 + a1) + (a2 + a3)) + Bv[tid]);
    }
    if (tid == 0) out[STG_OFF + T_DEPTH] = dt;  // stg[T] = dt

    float r = 1.0f;     // read carry
    float acc = 0.f;
    {  // i = T (freshly pushed row)
      float coef = fminf(dt, fmaxf(0.f, r));
      if (tid < V_DIM) acc += coef * vt_local;
      r -= dt;
    }
    for (int i = T_DEPTH - 1; i >= 0; --i) {
      bool pop_active = (u > 0.f);
      if (!pop_active && r <= 0.f) break;   // below: sn == s (bulk copy correct), coef == 0
      float s  = prev_stg[i];               // wave-uniform load
      float sn = fmaxf(0.f, s - fmaxf(0.f, u));
      u -= sn;
      if (pop_active && tid == 0) out[STG_OFF + i] = sn;
      float coef = fminf(sn, fmaxf(0.f, r));
      r -= sn;
      if (coef > 0.f && tid < V_DIM) acc += coef * prev_val[i * V_DIM + tid];
    }
    if (tid < V_DIM) out[RT_OFF + tid] = acc;
  }
}

extern "C" void kernel_launch(void* const* d_in, const int* in_sizes, int n_in,
                              void* d_out, int out_size, void* d_ws, size_t ws_size,
                              hipStream_t stream) {
  (void)in_sizes; (void)n_in; (void)out_size; (void)ws_size;
  const float* input     = (const float*)d_in[0];
  const float* prev_Val  = (const float*)d_in[1];
  const float* prev_stg  = (const float*)d_in[2];
  const float* prev_read = (const float*)d_in[3];
  const float* prev_h    = (const float*)d_in[4];
  const float* prev_c    = (const float*)d_in[5];
  const float* W_ih0 = (const float*)d_in[6];
  const float* W_hh0 = (const float*)d_in[7];
  const float* b_ih0 = (const float*)d_in[8];
  const float* b_hh0 = (const float*)d_in[9];
  const float* W_ih1 = (const float*)d_in[10];
  const float* W_hh1 = (const float*)d_in[11];
  const float* b_ih1 = (const float*)d_in[12];
  const float* b_hh1 = (const float*)d_in[13];
  const float* Wd = (const float*)d_in[14];
  const float* Bd = (const float*)d_in[15];
  const float* Wu = (const float*)d_in[16];
  const float* Bu = (const float*)d_in[17];
  const float* Wv = (const float*)d_in[18];
  const float* Bv = (const float*)d_in[19];
  const float* Wo = (const float*)d_in[20];
  const float* Bo = (const float*)d_in[21];

  float* out = (float*)d_out;
  float* ws  = (float*)d_ws;

  // 4 stream ops. k_bulk8 is the A/B under test: 8-deep load batching +
  // cached loads / NT stores. ktail must stay after k_bulk8 (stg head rewrite).
  k_bulk8<<<CB, 256, 0, stream>>>((const f32x4*)prev_Val, (const f32x2*)prev_stg, out);
  kL0<<<128, 256, 0, stream>>>(W_ih0, W_hh0, b_ih0, b_hh0, input, prev_read,
                               prev_h, prev_c, ws, out);
  kL1<<<128, 256, 0, stream>>>(W_ih1, W_hh1, b_ih1, b_hh1,
                               prev_h + H_DIM, prev_c + H_DIM, ws, out);
  ktail<<<4, 256, 0, stream>>>(Wv, Bv, Wo, Bo, Wd, Bd, Wu, Bu,
                               prev_stg, prev_Val, ws, out);
}

// Round 7
// 306.740 us; speedup vs baseline: 1.0266x; 1.0266x over previous
//
#include <hip/hip_runtime.h>

#define T_DEPTH 200000
#define V_DIM   130
#define H_DIM   512

// d_out offsets (fp32 elements): ot, Val, stg, rt, h_new, c_new
#define OT_OFF   0
#define VAL_OFF  512
#define STG_OFF  26000642
#define RT_OFF   26200643
#define HN_OFF   26200773
#define CN_OFF   26201797

// ws offsets (floats) — all written before read, no memset needed
#define WS_H1    64
#define WS_C1    576
#define WS_H2    1088
#define WS_C2    1600

static __device__ __forceinline__ float sigmoidf_(float x) {
  return 1.0f / (1.0f + expf(-x));
}

// one wave computes all 4 gate dots for unit j, then lane 0 applies the cell.
// (verified rounds 3-6) x = x_a (+ x_b if non-null)
static __device__ __forceinline__ void lstm_unit(
    const float* __restrict__ Wih, int in_dim,
    const float* __restrict__ x_a, const float* __restrict__ x_b,
    const float* __restrict__ Whh, const float* __restrict__ hprev,
    const float* __restrict__ bih, const float* __restrict__ bhh,
    const float* __restrict__ cprev, int j, int lane,
    float* __restrict__ h_ws, float* __restrict__ c_ws,
    float* __restrict__ h_out, float* __restrict__ c_out) {
  float pg[4];
#pragma unroll
  for (int q = 0; q < 4; ++q) {
    int row = q * H_DIM + j;
    const float* wr = Wih + row * in_dim;
    const float* wh = Whh + row * H_DIM;
    float acc = 0.f;
    if (x_b) {
      for (int c = lane; c < in_dim; c += 64) acc += wr[c] * (x_a[c] + x_b[c]);
    } else {
      for (int c = lane; c < in_dim; c += 64) acc += wr[c] * x_a[c];
    }
    for (int k = lane; k < H_DIM; k += 64) acc += wh[k] * hprev[k];
    for (int off = 32; off; off >>= 1) acc += __shfl_down(acc, off, 64);
    pg[q] = acc;  // total valid on lane 0
  }
  if (lane == 0) {
    float ig = sigmoidf_(pg[0] + bih[j] + bhh[j]);
    float fg = sigmoidf_(pg[1] + bih[H_DIM + j] + bhh[H_DIM + j]);
    float gg = tanhf(pg[2] + bih[2 * H_DIM + j] + bhh[2 * H_DIM + j]);
    float og = sigmoidf_(pg[3] + bih[3 * H_DIM + j] + bhh[3 * H_DIM + j]);
    float cn = fg * cprev[j] + ig * gg;
    float hn = og * tanhf(cn);
    h_ws[j] = hn; c_ws[j] = cn;
    h_out[j] = hn; c_out[j] = cn;
  }
}

// ---- fused layer-0 gates + cell: 128 blocks, wave per unit
__global__ void kL0(const float* __restrict__ Wih, const float* __restrict__ Whh,
                    const float* __restrict__ bih, const float* __restrict__ bhh,
                    const float* __restrict__ inp, const float* __restrict__ prd,
                    const float* __restrict__ hprev, const float* __restrict__ cprev,
                    float* __restrict__ ws, float* __restrict__ out) {
  int j = blockIdx.x * 4 + (threadIdx.x >> 6), lane = threadIdx.x & 63;
  lstm_unit(Wih, V_DIM, inp, prd, Whh, hprev, bih, bhh, cprev, j, lane,
            ws + WS_H1, ws + WS_C1, out + HN_OFF, out + CN_OFF);
}

// ---- fused layer-1 gates + cell
__global__ void kL1(const float* __restrict__ Wih, const float* __restrict__ Whh,
                    const float* __restrict__ bih, const float* __restrict__ bhh,
                    const float* __restrict__ hprev, const float* __restrict__ cprev,
                    float* __restrict__ ws, float* __restrict__ out) {
  int j = blockIdx.x * 4 + (threadIdx.x >> 6), lane = threadIdx.x & 63;
  lstm_unit(Wih, H_DIM, ws + WS_H1, nullptr, Whh, hprev, bih, bhh, cprev, j, lane,
            ws + WS_H2, ws + WS_C2, out + HN_OFF + H_DIM, out + CN_OFF + H_DIM);
}

// ---- fused tail: heads + finalize + top-of-stack walk, 4 independent blocks.
// Block 3 recomputes dt/ut/vt locally so it has no cross-block deps. (verified r6)
__global__ void ktail(const float* __restrict__ Wv, const float* __restrict__ Bv,
                      const float* __restrict__ Wo, const float* __restrict__ Bo,
                      const float* __restrict__ Wd, const float* __restrict__ Bd,
                      const float* __restrict__ Wu, const float* __restrict__ Bu,
                      const float* __restrict__ prev_stg, const float* __restrict__ prev_val,
                      const float* __restrict__ ws, float* __restrict__ out) {
  int bid = blockIdx.x, tid = threadIdx.x;
  const float* h2 = ws + WS_H2;
  if (bid < 2) {
    // ot columns
    int t = bid * 256 + tid;
    float a0 = 0.f, a1 = 0.f, a2 = 0.f, a3 = 0.f;
    for (int k = 0; k < H_DIM; k += 4) {
      a0 += h2[k]     * Wo[k * H_DIM + t];
      a1 += h2[k + 1] * Wo[(k + 1) * H_DIM + t];
      a2 += h2[k + 2] * Wo[(k + 2) * H_DIM + t];
      a3 += h2[k + 3] * Wo[(k + 3) * H_DIM + t];
    }
    out[OT_OFF + t] = tanhf(((a0 + a1) + (a2 + a3)) + Bo[t]);
  } else if (bid == 2) {
    // vt -> Val row T (output only; walk block computes its own copy)
    if (tid < V_DIM) {
      float a0 = 0.f, a1 = 0.f, a2 = 0.f, a3 = 0.f;
      for (int k = 0; k < H_DIM; k += 4) {
        a0 += h2[k]     * Wv[k * V_DIM + tid];
        a1 += h2[k + 1] * Wv[(k + 1) * V_DIM + tid];
        a2 += h2[k + 2] * Wv[(k + 2) * V_DIM + tid];
        a3 += h2[k + 3] * Wv[(k + 3) * V_DIM + tid];
      }
      out[VAL_OFF + T_DEPTH * V_DIM + tid] = tanhf(((a0 + a1) + (a2 + a3)) + Bv[tid]);
    }
  } else {
    // walk block: local dt/ut (block reduce), local vt, then exact pop+read walk
    __shared__ float red[256];
    __shared__ float s_dt, s_ut;
    float pd = h2[tid] * Wd[tid] + h2[tid + 256] * Wd[tid + 256];
    float pu = h2[tid] * Wu[tid] + h2[tid + 256] * Wu[tid + 256];
    red[tid] = pd;
    __syncthreads();
    for (int s = 128; s; s >>= 1) {
      if (tid < s) red[tid] += red[tid + s];
      __syncthreads();
    }
    if (tid == 0) s_dt = sigmoidf_(red[0] + Bd[0]);
    __syncthreads();
    red[tid] = pu;
    __syncthreads();
    for (int s = 128; s; s >>= 1) {
      if (tid < s) red[tid] += red[tid + s];
      __syncthreads();
    }
    if (tid == 0) s_ut = sigmoidf_(red[0] + Bu[0]);
    __syncthreads();
    float dt = s_dt;
    float u  = s_ut;    // pop carry (starts at ut)

    float vt_local = 0.f;
    if (tid < V_DIM) {
      float a0 = 0.f, a1 = 0.f, a2 = 0.f, a3 = 0.f;
      for (int k = 0; k < H_DIM; k += 4) {
        a0 += h2[k]     * Wv[k * V_DIM + tid];
        a1 += h2[k + 1] * Wv[(k + 1) * V_DIM + tid];
        a2 += h2[k + 2] * Wv[(k + 2) * V_DIM + tid];
        a3 += h2[k + 3] * Wv[(k + 3) * V_DIM + tid];
      }
      vt_local = tanhf(((a0 + a1) + (a2 + a3)) + Bv[tid]);
    }
    if (tid == 0) out[STG_OFF + T_DEPTH] = dt;  // stg[T] = dt

    float r = 1.0f;     // read carry
    float acc = 0.f;
    {  // i = T (freshly pushed row)
      float coef = fminf(dt, fmaxf(0.f, r));
      if (tid < V_DIM) acc += coef * vt_local;
      r -= dt;
    }
    for (int i = T_DEPTH - 1; i >= 0; --i) {
      bool pop_active = (u > 0.f);
      if (!pop_active && r <= 0.f) break;   // below: sn == s (bulk copy correct), coef == 0
      float s  = prev_stg[i];               // wave-uniform load
      float sn = fmaxf(0.f, s - fmaxf(0.f, u));
      u -= sn;
      if (pop_active && tid == 0) out[STG_OFF + i] = sn;
      float coef = fminf(sn, fmaxf(0.f, r));
      r -= sn;
      if (coef > 0.f && tid < V_DIM) acc += coef * prev_val[i * V_DIM + tid];
    }
    if (tid < V_DIM) out[RT_OFF + tid] = acc;
  }
}

extern "C" void kernel_launch(void* const* d_in, const int* in_sizes, int n_in,
                              void* d_out, int out_size, void* d_ws, size_t ws_size,
                              hipStream_t stream) {
  (void)in_sizes; (void)n_in; (void)out_size; (void)ws_size;
  const float* input     = (const float*)d_in[0];
  const float* prev_Val  = (const float*)d_in[1];
  const float* prev_stg  = (const float*)d_in[2];
  const float* prev_read = (const float*)d_in[3];
  const float* prev_h    = (const float*)d_in[4];
  const float* prev_c    = (const float*)d_in[5];
  const float* W_ih0 = (const float*)d_in[6];
  const float* W_hh0 = (const float*)d_in[7];
  const float* b_ih0 = (const float*)d_in[8];
  const float* b_hh0 = (const float*)d_in[9];
  const float* W_ih1 = (const float*)d_in[10];
  const float* W_hh1 = (const float*)d_in[11];
  const float* b_ih1 = (const float*)d_in[12];
  const float* b_hh1 = (const float*)d_in[13];
  const float* Wd = (const float*)d_in[14];
  const float* Bd = (const float*)d_in[15];
  const float* Wu = (const float*)d_in[16];
  const float* Bu = (const float*)d_in[17];
  const float* Wv = (const float*)d_in[18];
  const float* Bv = (const float*)d_in[19];
  const float* Wo = (const float*)d_in[20];
  const float* Bo = (const float*)d_in[21];

  float* out = (float*)d_out;
  float* ws  = (float*)d_ws;

  // A/B experiment: vendor blit (rocclr copyBuffer, sibling of the 6.8 TB/s
  // fill kernel) for the compulsory bulk copy, instead of a hand-rolled kernel.
  // Val body: prev_Val -> out Val rows [0,T). stg body: prev_stg -> out stg [0,T).
  hipMemcpyAsync(out + VAL_OFF, prev_Val, (size_t)T_DEPTH * V_DIM * sizeof(float),
                 hipMemcpyDeviceToDevice, stream);
  hipMemcpyAsync(out + STG_OFF, prev_stg, (size_t)T_DEPTH * sizeof(float),
                 hipMemcpyDeviceToDevice, stream);

  // dependency chain (verified round 6); ktail rewrites the stg head and the
  // Val row T, stream-ordered after the memcpys.
  kL0<<<128, 256, 0, stream>>>(W_ih0, W_hh0, b_ih0, b_hh0, input, prev_read,
                               prev_h, prev_c, ws, out);
  kL1<<<128, 256, 0, stream>>>(W_ih1, W_hh1, b_ih1, b_hh1,
                               prev_h + H_DIM, prev_c + H_DIM, ws, out);
  ktail<<<4, 256, 0, stream>>>(Wv, Bv, Wo, Bo, Wd, Bd, Wu, Bu,
                               prev_stg, prev_Val, ws, out);
}

// Round 8
// 275.231 us; speedup vs baseline: 1.1442x; 1.1145x over previous
//
#include <hip/hip_runtime.h>

#define T_DEPTH 200000
#define V_DIM   130
#define H_DIM   512

// d_out offsets (fp32 elements): ot, Val, stg, rt, h_new, c_new
#define OT_OFF   0
#define VAL_OFF  512
#define STG_OFF  26000642
#define RT_OFF   26200643
#define HN_OFF   26200773
#define CN_OFF   26201797

// ws offsets (floats)
#define WS_G0     0
#define WS_H1     2048
#define WS_C1     2560
#define WS_G1     3072
#define WS_H2     5120
#define WS_C2     5632
#define WS_VTACC  6144
#define WS_OTACC  6274
#define WS_DTUT   6786
#define WS_VT     6788
#define WS_TOTAL  6918

static __device__ __forceinline__ float sigmoidf(float x) {
    return 1.0f / (1.0f + expf(-x));
}

// ---- big copy: prev_Val -> Val rows [0,T) (float4), prev_stg -> stg[0,T) (float2)
__global__ void k_bulk(const float4* __restrict__ val_in,
                       const float2* __restrict__ stg_in,
                       float* __restrict__ out) {
    const int NV4 = (T_DEPTH * V_DIM) / 4;   // 6,500,000
    const int NS2 = T_DEPTH / 2;             // 100,000
    const int NT  = NV4 + NS2;
    float4* __restrict__ val_out = reinterpret_cast<float4*>(out + VAL_OFF); // 16B aligned
    float2* __restrict__ stg_out = reinterpret_cast<float2*>(out + STG_OFF); // 8B aligned
    int stride = gridDim.x * blockDim.x;
    for (int u = blockIdx.x * blockDim.x + threadIdx.x; u < NT; u += stride) {
        if (u < NV4) {
            val_out[u] = val_in[u];
        } else {
            int s = u - NV4;
            stg_out[s] = stg_in[s];
        }
    }
}

// ---- layer-0 gates: g[row] = Wih0[row,:]·(input+prev_read) + Whh0[row,:]·h0 + b
__global__ void k_g0(const float* __restrict__ Wih, const float* __restrict__ Whh,
                     const float* __restrict__ bih, const float* __restrict__ bhh,
                     const float* __restrict__ inp, const float* __restrict__ prd,
                     const float* __restrict__ h0, float* __restrict__ g) {
    int wave = threadIdx.x >> 6, lane = threadIdx.x & 63;
    int row = blockIdx.x * 4 + wave;              // grid 512 -> rows 0..2047
    const float* wr = Wih + row * V_DIM;
    const float* wh = Whh + row * H_DIM;
    float p = 0.f;
    for (int c = lane; c < V_DIM; c += 64) p += wr[c] * (inp[c] + prd[c]);
    for (int k = lane; k < H_DIM; k += 64) p += wh[k] * h0[k];
    for (int off = 32; off; off >>= 1) p += __shfl_down(p, off, 64);
    if (lane == 0) g[row] = p + bih[row] + bhh[row];
}

// ---- layer-1 gates: g[row] = Wih1[row,:]·h1 + Whh1[row,:]·hprev + b
__global__ void k_g1(const float* __restrict__ Wih, const float* __restrict__ Whh,
                     const float* __restrict__ bih, const float* __restrict__ bhh,
                     const float* __restrict__ h1, const float* __restrict__ hprev,
                     float* __restrict__ g) {
    int wave = threadIdx.x >> 6, lane = threadIdx.x & 63;
    int row = blockIdx.x * 4 + wave;
    const float* wr = Wih + row * H_DIM;
    const float* wh = Whh + row * H_DIM;
    float p = 0.f;
    for (int k = lane; k < H_DIM; k += 64) p += wr[k] * h1[k] + wh[k] * hprev[k];
    for (int off = 32; off; off >>= 1) p += __shfl_down(p, off, 64);
    if (lane == 0) g[row] = p + bih[row] + bhh[row];
}

// ---- LSTM cell nonlinearity (gate order i,f,g,o per PyTorch layout)
__global__ void k_cell(const float* __restrict__ g, const float* __restrict__ cprev,
                       float* __restrict__ h, float* __restrict__ c,
                       float* __restrict__ h_out, float* __restrict__ c_out) {
    int j = threadIdx.x;  // 512
    float ig = sigmoidf(g[j]);
    float fg = sigmoidf(g[H_DIM + j]);
    float gg = tanhf(g[2 * H_DIM + j]);
    float og = sigmoidf(g[3 * H_DIM + j]);
    float cn = fg * cprev[j] + ig * gg;
    float hn = og * tanhf(cn);
    h[j] = hn; c[j] = cn;
    h_out[j] = hn;
    c_out[j] = cn;
}

// ---- heads: vt_acc[c] = sum_k h2[k]*Wv[k,c]; ot_acc[j] = sum_k h2[k]*Wo[k,j]
__global__ void k_heads(const float* __restrict__ h2, const float* __restrict__ Wv,
                        const float* __restrict__ Wo, float* __restrict__ vt_acc,
                        float* __restrict__ ot_acc) {
    int t = threadIdx.x;   // 256
    int b = blockIdx.x;    // 32 blocks, 16 k's each
    float a0 = 0.f, a1 = 0.f, av = 0.f;
    for (int kk = 0; kk < 16; ++kk) {
        int k = b * 16 + kk;
        float hv = h2[k];
        a0 += hv * Wo[k * H_DIM + t];
        a1 += hv * Wo[k * H_DIM + t + 256];
        if (t < V_DIM) av += hv * Wv[k * V_DIM + t];
    }
    atomicAdd(&ot_acc[t], a0);
    atomicAdd(&ot_acc[t + 256], a1);
    if (t < V_DIM) atomicAdd(&vt_acc[t], av);
}

// ---- finalize heads: dt/ut dots, tanh for vt/ot, write ot / Val row T / stg[T]
__global__ void k_hfin(const float* __restrict__ h2,
                       const float* __restrict__ Wd, const float* __restrict__ Bd,
                       const float* __restrict__ Wu, const float* __restrict__ Bu,
                       const float* __restrict__ Bv, const float* __restrict__ Bo,
                       const float* __restrict__ vt_acc, const float* __restrict__ ot_acc,
                       float* __restrict__ dtut, float* __restrict__ vt,
                       float* __restrict__ out) {
    __shared__ float sd[H_DIM], su[H_DIM];
    int t = threadIdx.x;  // 512
    sd[t] = h2[t] * Wd[t];
    su[t] = h2[t] * Wu[t];
    __syncthreads();
    for (int s = 256; s; s >>= 1) {
        if (t < s) { sd[t] += sd[t + s]; su[t] += su[t + s]; }
        __syncthreads();
    }
    if (t == 0) {
        float dt = sigmoidf(sd[0] + Bd[0]);
        float ut = sigmoidf(su[0] + Bu[0]);
        dtut[0] = dt; dtut[1] = ut;
        out[STG_OFF + T_DEPTH] = dt;             // stg[T] = dt
    }
    float ot = tanhf(ot_acc[t] + Bo[t]);
    out[OT_OFF + t] = ot;
    if (t < V_DIM) {
        float v = tanhf(vt_acc[t] + Bv[t]);
        vt[t] = v;
        out[VAL_OFF + T_DEPTH * V_DIM + t] = v;  // Val row T = vt
    }
}

// ---- fused top walk: exact pop-scan head rewrite + exact early-terminated rt
__global__ void k_top(const float* __restrict__ prev_stg, const float* __restrict__ prev_val,
                      const float* __restrict__ dtut, const float* __restrict__ vt,
                      float* __restrict__ out) {
    int t = threadIdx.x;  // 192
    float dt = dtut[0];
    float u  = dtut[1];   // pop carry (starts at ut)
    float r  = 1.0f;      // read carry
    float acc = 0.f;
    // i = T (freshly pushed row): stg[T]=dt (already written), coef = min(dt, max(0,r))
    {
        float coef = fminf(dt, fmaxf(0.f, r));
        if (t < V_DIM) acc += coef * vt[t];
        r -= dt;
    }
    for (int i = T_DEPTH - 1; i >= 0; --i) {
        bool pop_active = (u > 0.f);
        if (!pop_active && r <= 0.f) break;   // below: sn == s (bulk copy correct), coef == 0
        float s  = prev_stg[i];               // wave-uniform load
        float sn = fmaxf(0.f, s - fmaxf(0.f, u));
        u -= sn;
        if (pop_active && t == 0) out[STG_OFF + i] = sn;
        float coef = fminf(sn, fmaxf(0.f, r));
        r -= sn;
        if (coef > 0.f && t < V_DIM) acc += coef * prev_val[i * V_DIM + t];
    }
    if (t < V_DIM) out[RT_OFF + t] = acc;
}

extern "C" void kernel_launch(void* const* d_in, const int* in_sizes, int n_in,
                              void* d_out, int out_size, void* d_ws, size_t ws_size,
                              hipStream_t stream) {
    (void)in_sizes; (void)n_in; (void)out_size; (void)ws_size;
    const float* input     = (const float*)d_in[0];
    const float* prev_Val  = (const float*)d_in[1];
    const float* prev_stg  = (const float*)d_in[2];
    const float* prev_read = (const float*)d_in[3];
    const float* prev_h    = (const float*)d_in[4];
    const float* prev_c    = (const float*)d_in[5];
    const float* W_ih0 = (const float*)d_in[6];
    const float* W_hh0 = (const float*)d_in[7];
    const float* b_ih0 = (const float*)d_in[8];
    const float* b_hh0 = (const float*)d_in[9];
    const float* W_ih1 = (const float*)d_in[10];
    const float* W_hh1 = (const float*)d_in[11];
    const float* b_ih1 = (const float*)d_in[12];
    const float* b_hh1 = (const float*)d_in[13];
    const float* Wd = (const float*)d_in[14];
    const float* Bd = (const float*)d_in[15];
    const float* Wu = (const float*)d_in[16];
    const float* Bu = (const float*)d_in[17];
    const float* Wv = (const float*)d_in[18];
    const float* Bv = (const float*)d_in[19];
    const float* Wo = (const float*)d_in[20];
    const float* Bo = (const float*)d_in[21];

    float* out = (float*)d_out;
    float* ws  = (float*)d_ws;

    // zero the small ws accumulators (ws is poisoned 0xAA before every launch)
    hipMemsetAsync(d_ws, 0, WS_TOTAL * sizeof(float), stream);

    // big streaming copy (independent of everything; stg head fixed later by k_top)
    k_bulk<<<4096, 256, 0, stream>>>((const float4*)prev_Val, (const float2*)prev_stg, out);

    // LSTM chain
    k_g0<<<512, 256, 0, stream>>>(W_ih0, W_hh0, b_ih0, b_hh0, input, prev_read,
                                  prev_h, ws + WS_G0);
    k_cell<<<1, 512, 0, stream>>>(ws + WS_G0, prev_c, ws + WS_H1, ws + WS_C1,
                                  out + HN_OFF, out + CN_OFF);
    k_g1<<<512, 256, 0, stream>>>(W_ih1, W_hh1, b_ih1, b_hh1, ws + WS_H1,
                                  prev_h + H_DIM, ws + WS_G1);
    k_cell<<<1, 512, 0, stream>>>(ws + WS_G1, prev_c + H_DIM, ws + WS_H2, ws + WS_C2,
                                  out + HN_OFF + H_DIM, out + CN_OFF + H_DIM);

    // heads
    k_heads<<<32, 256, 0, stream>>>(ws + WS_H2, Wv, Wo, ws + WS_VTACC, ws + WS_OTACC);
    k_hfin<<<1, 512, 0, stream>>>(ws + WS_H2, Wd, Bd, Wu, Bu, Bv, Bo,
                                  ws + WS_VTACC, ws + WS_OTACC,
                                  ws + WS_DTUT, ws + WS_VT, out);

    // exact top-of-stack walk: pop head + rt
    k_top<<<1, 192, 0, stream>>>(prev_stg, prev_Val, ws + WS_DTUT, ws + WS_VT, out);
}

// Round 9
// 271.563 us; speedup vs baseline: 1.1596x; 1.0135x over previous
//
#include <hip/hip_runtime.h>

#define T_DEPTH 200000
#define V_DIM   130
#define H_DIM   512

// d_out offsets (fp32 elements): ot, Val, stg, rt, h_new, c_new
#define OT_OFF   0
#define VAL_OFF  512
#define STG_OFF  26000642
#define RT_OFF   26200643
#define HN_OFF   26200773
#define CN_OFF   26201797

// ws offsets (floats)
#define WS_G0     0
#define WS_H1     2048
#define WS_C1     2560
#define WS_G1     3072
#define WS_H2     5120
#define WS_C2     5632
#define WS_VTACC  6144
#define WS_OTACC  6274
#define WS_DTUT   6786
#define WS_VT     6788
#define WS_TOTAL  6918

static __device__ __forceinline__ float sigmoidf(float x) {
    return 1.0f / (1.0f + expf(-x));
}

// ---- layer-0 gates: g[row] = Wih0[row,:]·(input+prev_read) + Whh0[row,:]·h0 + b
__global__ void k_g0(const float* __restrict__ Wih, const float* __restrict__ Whh,
                     const float* __restrict__ bih, const float* __restrict__ bhh,
                     const float* __restrict__ inp, const float* __restrict__ prd,
                     const float* __restrict__ h0, float* __restrict__ g) {
    int wave = threadIdx.x >> 6, lane = threadIdx.x & 63;
    int row = blockIdx.x * 4 + wave;              // grid 512 -> rows 0..2047
    const float* wr = Wih + row * V_DIM;
    const float* wh = Whh + row * H_DIM;
    float p = 0.f;
    for (int c = lane; c < V_DIM; c += 64) p += wr[c] * (inp[c] + prd[c]);
    for (int k = lane; k < H_DIM; k += 64) p += wh[k] * h0[k];
    for (int off = 32; off; off >>= 1) p += __shfl_down(p, off, 64);
    if (lane == 0) g[row] = p + bih[row] + bhh[row];
}

// ---- layer-1 gates: g[row] = Wih1[row,:]·h1 + Whh1[row,:]·hprev + b
__global__ void k_g1(const float* __restrict__ Wih, const float* __restrict__ Whh,
                     const float* __restrict__ bih, const float* __restrict__ bhh,
                     const float* __restrict__ h1, const float* __restrict__ hprev,
                     float* __restrict__ g) {
    int wave = threadIdx.x >> 6, lane = threadIdx.x & 63;
    int row = blockIdx.x * 4 + wave;
    const float* wr = Wih + row * H_DIM;
    const float* wh = Whh + row * H_DIM;
    float p = 0.f;
    for (int k = lane; k < H_DIM; k += 64) p += wr[k] * h1[k] + wh[k] * hprev[k];
    for (int off = 32; off; off >>= 1) p += __shfl_down(p, off, 64);
    if (lane == 0) g[row] = p + bih[row] + bhh[row];
}

// ---- LSTM cell nonlinearity (gate order i,f,g,o per PyTorch layout)
__global__ void k_cell(const float* __restrict__ g, const float* __restrict__ cprev,
                       float* __restrict__ h, float* __restrict__ c,
                       float* __restrict__ h_out, float* __restrict__ c_out) {
    int j = threadIdx.x;  // 512
    float ig = sigmoidf(g[j]);
    float fg = sigmoidf(g[H_DIM + j]);
    float gg = tanhf(g[2 * H_DIM + j]);
    float og = sigmoidf(g[3 * H_DIM + j]);
    float cn = fg * cprev[j] + ig * gg;
    float hn = og * tanhf(cn);
    h[j] = hn; c[j] = cn;
    h_out[j] = hn;
    c_out[j] = cn;
}

// ---- heads: vt_acc[c] = sum_k h2[k]*Wv[k,c]; ot_acc[j] = sum_k h2[k]*Wo[k,j]
__global__ void k_heads(const float* __restrict__ h2, const float* __restrict__ Wv,
                        const float* __restrict__ Wo, float* __restrict__ vt_acc,
                        float* __restrict__ ot_acc) {
    int t = threadIdx.x;   // 256
    int b = blockIdx.x;    // 32 blocks, 16 k's each
    float a0 = 0.f, a1 = 0.f, av = 0.f;
    for (int kk = 0; kk < 16; ++kk) {
        int k = b * 16 + kk;
        float hv = h2[k];
        a0 += hv * Wo[k * H_DIM + t];
        a1 += hv * Wo[k * H_DIM + t + 256];
        if (t < V_DIM) av += hv * Wv[k * V_DIM + t];
    }
    atomicAdd(&ot_acc[t], a0);
    atomicAdd(&ot_acc[t + 256], a1);
    if (t < V_DIM) atomicAdd(&vt_acc[t], av);
}

// ---- finalize heads: dt/ut dots, tanh for vt/ot, write ot / Val row T / stg[T]
__global__ void k_hfin(const float* __restrict__ h2,
                       const float* __restrict__ Wd, const float* __restrict__ Bd,
                       const float* __restrict__ Wu, const float* __restrict__ Bu,
                       const float* __restrict__ Bv, const float* __restrict__ Bo,
                       const float* __restrict__ vt_acc, const float* __restrict__ ot_acc,
                       float* __restrict__ dtut, float* __restrict__ vt,
                       float* __restrict__ out) {
    __shared__ float sd[H_DIM], su[H_DIM];
    int t = threadIdx.x;  // 512
    sd[t] = h2[t] * Wd[t];
    su[t] = h2[t] * Wu[t];
    __syncthreads();
    for (int s = 256; s; s >>= 1) {
        if (t < s) { sd[t] += sd[t + s]; su[t] += su[t + s]; }
        __syncthreads();
    }
    if (t == 0) {
        float dt = sigmoidf(sd[0] + Bd[0]);
        float ut = sigmoidf(su[0] + Bu[0]);
        dtut[0] = dt; dtut[1] = ut;
        out[STG_OFF + T_DEPTH] = dt;             // stg[T] = dt
    }
    float ot = tanhf(ot_acc[t] + Bo[t]);
    out[OT_OFF + t] = ot;
    if (t < V_DIM) {
        float v = tanhf(vt_acc[t] + Bv[t]);
        vt[t] = v;
        out[VAL_OFF + T_DEPTH * V_DIM + t] = v;  // Val row T = vt
    }
}

// ---- fused top walk: exact pop-scan head rewrite + exact early-terminated rt
__global__ void k_top(const float* __restrict__ prev_stg, const float* __restrict__ prev_val,
                      const float* __restrict__ dtut, const float* __restrict__ vt,
                      float* __restrict__ out) {
    int t = threadIdx.x;  // 192
    float dt = dtut[0];
    float u  = dtut[1];   // pop carry (starts at ut)
    float r  = 1.0f;      // read carry
    float acc = 0.f;
    // i = T (freshly pushed row): stg[T]=dt (already written), coef = min(dt, max(0,r))
    {
        float coef = fminf(dt, fmaxf(0.f, r));
        if (t < V_DIM) acc += coef * vt[t];
        r -= dt;
    }
    for (int i = T_DEPTH - 1; i >= 0; --i) {
        bool pop_active = (u > 0.f);
        if (!pop_active && r <= 0.f) break;   // below: sn == s (bulk copy correct), coef == 0
        float s  = prev_stg[i];               // wave-uniform load
        float sn = fmaxf(0.f, s - fmaxf(0.f, u));
        u -= sn;
        if (pop_active && t == 0) out[STG_OFF + i] = sn;
        float coef = fminf(sn, fmaxf(0.f, r));
        r -= sn;
        if (coef > 0.f && t < V_DIM) acc += coef * prev_val[i * V_DIM + t];
    }
    if (t < V_DIM) out[RT_OFF + t] = acc;
}

extern "C" void kernel_launch(void* const* d_in, const int* in_sizes, int n_in,
                              void* d_out, int out_size, void* d_ws, size_t ws_size,
                              hipStream_t stream) {
    (void)in_sizes; (void)n_in; (void)out_size; (void)ws_size;
    const float* input     = (const float*)d_in[0];
    const float* prev_Val  = (const float*)d_in[1];
    const float* prev_stg  = (const float*)d_in[2];
    const float* prev_read = (const float*)d_in[3];
    const float* prev_h    = (const float*)d_in[4];
    const float* prev_c    = (const float*)d_in[5];
    const float* W_ih0 = (const float*)d_in[6];
    const float* W_hh0 = (const float*)d_in[7];
    const float* b_ih0 = (const float*)d_in[8];
    const float* b_hh0 = (const float*)d_in[9];
    const float* W_ih1 = (const float*)d_in[10];
    const float* W_hh1 = (const float*)d_in[11];
    const float* b_ih1 = (const float*)d_in[12];
    const float* b_hh1 = (const float*)d_in[13];
    const float* Wd = (const float*)d_in[14];
    const float* Bd = (const float*)d_in[15];
    const float* Wu = (const float*)d_in[16];
    const float* Bu = (const float*)d_in[17];
    const float* Wv = (const float*)d_in[18];
    const float* Bv = (const float*)d_in[19];
    const float* Wo = (const float*)d_in[20];
    const float* Bo = (const float*)d_in[21];

    float* out = (float*)d_out;
    float* ws  = (float*)d_ws;

    // zero the small ws accumulators (ws is poisoned 0xAA before every launch)
    hipMemsetAsync(d_ws, 0, WS_TOTAL * sizeof(float), stream);

    // ONE CHANGE vs round 8: bulk copy via vendor blit (rocclr copyBuffer,
    // sibling of the 6.8 TB/s fill kernel) instead of hand-rolled k_bulk
    // (61 us @ 2.5 TB/s). Chain and everything else byte-identical to the
    // verified 275 us structure. stg head rows fixed later by k_top.
    hipMemcpyAsync(out + VAL_OFF, prev_Val, (size_t)T_DEPTH * V_DIM * sizeof(float),
                   hipMemcpyDeviceToDevice, stream);
    hipMemcpyAsync(out + STG_OFF, prev_stg, (size_t)T_DEPTH * sizeof(float),
                   hipMemcpyDeviceToDevice, stream);

    // LSTM chain
    k_g0<<<512, 256, 0, stream>>>(W_ih0, W_hh0, b_ih0, b_hh0, input, prev_read,
                                  prev_h, ws + WS_G0);
    k_cell<<<1, 512, 0, stream>>>(ws + WS_G0, prev_c, ws + WS_H1, ws + WS_C1,
                                  out + HN_OFF, out + CN_OFF);
    k_g1<<<512, 256, 0, stream>>>(W_ih1, W_hh1, b_ih1, b_hh1, ws + WS_H1,
                                  prev_h + H_DIM, ws + WS_G1);
    k_cell<<<1, 512, 0, stream>>>(ws + WS_G1, prev_c + H_DIM, ws + WS_H2, ws + WS_C2,
                                  out + HN_OFF + H_DIM, out + CN_OFF + H_DIM);

    // heads
    k_heads<<<32, 256, 0, stream>>>(ws + WS_H2, Wv, Wo, ws + WS_VTACC, ws + WS_OTACC);
    k_hfin<<<1, 512, 0, stream>>>(ws + WS_H2, Wd, Bd, Wu, Bu, Bv, Bo,
                                  ws + WS_VTACC, ws + WS_OTACC,
                                  ws + WS_DTUT, ws + WS_VT, out);

    // exact top-of-stack walk: pop head + rt
    k_top<<<1, 192, 0, stream>>>(prev_stg, prev_Val, ws + WS_DTUT, ws + WS_VT, out);
}